// Round 15
// baseline (388.038 us; speedup 1.0000x reference)
//
#include <hip/hip_runtime.h>
#include <cmath>

// ---------------------------------------------------------------------------
// Problem constants: B=16, N=196, D=512, M=20, H=8, hd=64, k=51
//   tokens = 3136, 3D = 1536
// Algebra: h1 = Omg@(W1*Wo)^T + F@W1^T + (W1*bo + b1)  [Fenh eliminated]
// R14 pipeline (proven 314us) + this round:
//   - T14 async-stage (preload next chunk; issue loads before MFMA) in both
//     GEMMs, __launch_bounds__(256,3) to protect 3-blocks/CU occupancy
//   - XCD swizzle on qkvw GEMM (400 blocks, bijective)
//   - quaternary (3-midpoint) select search: serial chain ~halved
//   - write kernel: 2 blocks per bn (grid 6272)
// ---------------------------------------------------------------------------

typedef __attribute__((ext_vector_type(8))) short bf16x8v;
typedef __attribute__((ext_vector_type(4))) float f32x4v;

__device__ __forceinline__ unsigned short f2bf_rne(float x) {
  unsigned u = __float_as_uint(x);
  u += 0x7fffu + ((u >> 16) & 1u);   // round-to-nearest-even
  return (unsigned short)(u >> 16);
}
__device__ __forceinline__ float bf2f(unsigned short h) {
  return __uint_as_float(((unsigned)h) << 16);
}
__device__ __forceinline__ void split3_1(float x,
    unsigned short& s0, unsigned short& s1, unsigned short& s2) {
  s0 = f2bf_rne(x); float r1 = x - bf2f(s0);
  s1 = f2bf_rne(r1); float r2 = r1 - bf2f(s1);
  s2 = f2bf_rne(r2);
}

// ---------------------------------------------------------------------------
// prep mega-kernel (unchanged from R14).
// ---------------------------------------------------------------------------
__global__ __launch_bounds__(256) void prep_kernel(
    const float* __restrict__ F, unsigned short* __restrict__ Fs,
    const float* __restrict__ Wqkv, const float* __restrict__ W1,
    unsigned short* __restrict__ Walls,
    const float* __restrict__ Wo, unsigned short* __restrict__ Wcs,
    float* __restrict__ Vt,
    const float* __restrict__ bo, const float* __restrict__ b1,
    float* __restrict__ bcomb,
    const float* __restrict__ bqkv, float* __restrict__ biasAll)
{
  int b = blockIdx.x;
  int tid = threadIdx.x;

  if (b < 1296) {  // ---- splits ----
    const float* X; unsigned short* O; long long i8, pstride;
    if (b < 784)       { X = F;    O = Fs;              pstride = 1605632; i8 = (long long)b * 256 + tid; }
    else if (b < 1168) { X = Wqkv; O = Walls;           pstride = 1048576; i8 = (long long)(b - 784) * 256 + tid; }
    else               { X = W1;   O = Walls + 786432;  pstride = 1048576; i8 = (long long)(b - 1168) * 256 + tid; }
    const float4 aa = *(const float4*)(X + i8 * 8);
    const float4 bb = *(const float4*)(X + i8 * 8 + 4);
    float xs[8] = {aa.x, aa.y, aa.z, aa.w, bb.x, bb.y, bb.z, bb.w};
    bf16x8v o0, o1, o2;
#pragma unroll
    for (int e = 0; e < 8; e++) {
      unsigned short s0, s1, s2;
      split3_1(xs[e], s0, s1, s2);
      o0[e] = (short)s0; o1[e] = (short)s1; o2[e] = (short)s2;
    }
    *(bf16x8v*)(O + i8 * 8)               = o0;
    *(bf16x8v*)(O + pstride + i8 * 8)     = o1;
    *(bf16x8v*)(O + 2 * pstride + i8 * 8) = o2;
    return;
  }

  if (b < 1360) {  // ---- Wc = W1 @ Wo, 64x64 tile, limb output ----
    __shared__ __align__(16) float As[16][68];
    __shared__ __align__(16) float Bs[16][68];
    int local = b - 1296;
    int i0 = (local >> 3) * 64, j0 = (local & 7) * 64;
    int tx = tid & 15, ty = tid >> 4;
    double acc[4][4];
#pragma unroll
    for (int i = 0; i < 4; i++)
#pragma unroll
      for (int j = 0; j < 4; j++) acc[i][j] = 0.0;
    for (int k0 = 0; k0 < 512; k0 += 16) {
#pragma unroll
      for (int rr = 0; rr < 4; rr++) {
        int r = ty + 16 * rr;
        As[tx][r] = W1[(size_t)(i0 + r) * 512 + k0 + tx];
      }
      {
        int j = tid & 63, c0 = (tid >> 6) * 4;
#pragma unroll
        for (int cc = 0; cc < 4; cc++) {
          int c = c0 + cc;
          Bs[c][j] = Wo[(size_t)(k0 + c) * 512 + j0 + j];
        }
      }
      __syncthreads();
      float cf[4][4];
#pragma unroll
      for (int i = 0; i < 4; i++)
#pragma unroll
        for (int j = 0; j < 4; j++) cf[i][j] = 0.0f;
#pragma unroll
      for (int kk = 0; kk < 16; kk++) {
        float4 a4 = *(const float4*)&As[kk][ty * 4];
        float4 b4 = *(const float4*)&Bs[kk][tx * 4];
        float av[4] = {a4.x, a4.y, a4.z, a4.w};
        float bv[4] = {b4.x, b4.y, b4.z, b4.w};
#pragma unroll
        for (int i = 0; i < 4; i++)
#pragma unroll
          for (int j = 0; j < 4; j++) cf[i][j] = fmaf(av[i], bv[j], cf[i][j]);
      }
#pragma unroll
      for (int i = 0; i < 4; i++)
#pragma unroll
        for (int j = 0; j < 4; j++) acc[i][j] += (double)cf[i][j];
      __syncthreads();
    }
#pragma unroll
    for (int i = 0; i < 4; i++) {
      int gi = i0 + ty * 4 + i;
#pragma unroll
      for (int j = 0; j < 4; j++) {
        int gj = j0 + tx * 4 + j;
        float o = (float)acc[i][j];
        unsigned short l0, l1, l2;
        split3_1(o, l0, l1, l2);
        size_t idx = (size_t)gi * 512 + gj;
        Wcs[idx] = l0; Wcs[idx + 262144] = l1; Wcs[idx + 524288] = l2;
      }
    }
    return;
  }

  if (b < 1472) {  // ---- zero Vt pad: 128 z x 64 d x 28 kk = 229376 ----
    long long p0 = (long long)(b - 1360) * 2048 + tid * 8;
#pragma unroll
    for (int e = 0; e < 8; e++) {
      long long pf = p0 + e;
      int z = (int)(pf / 1792);
      int r = (int)(pf - (long long)z * 1792);
      int d = r / 28, kk = r - d * 28;
      Vt[(size_t)z * 14336 + (size_t)d * 224 + 196 + kk] = 0.0f;
    }
    return;
  }

  if (b == 1472) {  // ---- bcomb ----
#pragma unroll
    for (int half = 0; half < 2; half++) {
      int n = tid + half * 256;
      const float* wr = W1 + (size_t)n * 512;
      double acc = 0.0;
      for (int k = 0; k < 512; k += 4) {
        float4 wv = *(const float4*)&wr[k];
        float4 bv = *(const float4*)&bo[k];
        acc += (double)wv.x * bv.x + (double)wv.y * bv.y +
               (double)wv.z * bv.z + (double)wv.w * bv.w;
      }
      bcomb[n] = (float)(acc + (double)b1[n]);
    }
    return;
  }

  // b == 1473: biasAll
#pragma unroll
  for (int e = 0; e < 8; e++) {
    int idx = tid * 8 + e;
    biasAll[idx] = (idx < 1536) ? bqkv[idx] : 0.0f;
  }
}

#define GBK 32
// Row-interleaved limb LDS layout: per row [s0 64B | s1 64B | s2 64B | 16B pad]
#define ROWB 208                 // bytes per row
#define ATILE (128 * ROWB)       // 26624 B per operand tile; total 53248 B

// ---------------------------------------------------------------------------
// Pre-split bf16x3 MFMA GEMM with T14 async-stage (preload chunk0, issue
// next-chunk loads BEFORE the MFMA phase so HBM latency drains under MFMA).
// xcdSwz: bijective XCD remap of flat block id (requires nwg%8==0, z==1).
// ---------------------------------------------------------------------------
__global__ __launch_bounds__(256, 3) void gemm_ps3_kernel(
    const unsigned short* __restrict__ As, const unsigned short* __restrict__ Bs,
    float* __restrict__ C, const float* __restrict__ bias,
    const float* __restrict__ res,
    int M, int N, int ldc, int ldres,
    long long aPlane, long long bPlane,
    int kLen, long long cZStride,
    float* __restrict__ VtOut, int xcdSwz)
{
  __shared__ __align__(16) unsigned char smem[2 * ATILE];  // 53248 B -> 3 blk/CU

  int z = blockIdx.z;
  int kOff = z * kLen;
  C += (size_t)z * cZStride;

  int bx = blockIdx.x, by = blockIdx.y;
  if (xcdSwz) {
    int nwg = gridDim.x * gridDim.y;
    int flat = bx + gridDim.x * by;
    flat = (flat & 7) * (nwg >> 3) + (flat >> 3);   // nwg % 8 == 0
    bx = flat % gridDim.x;
    by = flat / gridDim.x;
  }

  int tid = threadIdx.x;
  int lane = tid & 63, w = tid >> 6;
  int wrow = w >> 1, wcol = w & 1;
  int i0 = bx * 128, j0 = by * 128;

  int r = tid >> 1, hh = tid & 1;
  int arow = i0 + r; if (arow > M - 1) arow = M - 1;
  int brow = j0 + r; if (brow > N - 1) brow = N - 1;
  const unsigned short* ap = As + (size_t)arow * 512 + hh * 16 + kOff;
  const unsigned short* bp = Bs + (size_t)brow * 512 + hh * 16 + kOff;
  unsigned swoff = (unsigned)r * ROWB + (unsigned)hh * 32;

  f32x4v acc[4][4];
#pragma unroll
  for (int fi = 0; fi < 4; fi++)
#pragma unroll
    for (int fj = 0; fj < 4; fj++) acc[fi][fj] = (f32x4v){0.f, 0.f, 0.f, 0.f};

  unsigned fr_a = (unsigned)(wrow * 64 + (lane & 15)) * ROWB + (unsigned)(lane >> 4) * 16;
  unsigned fr_b = (unsigned)(wcol * 64 + (lane & 15)) * ROWB + (unsigned)(lane >> 4) * 16 + ATILE;

  bf16x8v a0[3], a1[3], b0v[3], b1v[3];
#define PS3_LOAD(K0)                                            \
  _Pragma("unroll")                                             \
  for (int s = 0; s < 3; s++) {                                 \
    a0[s]  = *(const bf16x8v*)(ap + s * aPlane + (K0));         \
    a1[s]  = *(const bf16x8v*)(ap + s * aPlane + (K0) + 8);     \
    b0v[s] = *(const bf16x8v*)(bp + s * bPlane + (K0));         \
    b1v[s] = *(const bf16x8v*)(bp + s * bPlane + (K0) + 8);     \
  }

  PS3_LOAD(0);
  for (int k0 = 0; k0 < kLen; k0 += GBK) {
    __syncthreads();  // previous chunk's frag reads complete
#pragma unroll
    for (int s = 0; s < 3; s++) {
      *(bf16x8v*)(smem + swoff + s * 64)              = a0[s];
      *(bf16x8v*)(smem + swoff + s * 64 + 16)         = a1[s];
      *(bf16x8v*)(smem + ATILE + swoff + s * 64)      = b0v[s];
      *(bf16x8v*)(smem + ATILE + swoff + s * 64 + 16) = b1v[s];
    }
    __syncthreads();

    if (k0 + GBK < kLen) { PS3_LOAD(k0 + GBK); }   // latency hides under MFMA

    bf16x8v af[4][3];
#pragma unroll
    for (int fi = 0; fi < 4; fi++)
#pragma unroll
      for (int s = 0; s < 3; s++)
        af[fi][s] = *(const bf16x8v*)(smem + fr_a + fi * (16 * ROWB) + s * 64);

#pragma unroll
    for (int fj = 0; fj < 4; fj++) {
      bf16x8v b0 = *(const bf16x8v*)(smem + fr_b + fj * (16 * ROWB));
      bf16x8v b1 = *(const bf16x8v*)(smem + fr_b + fj * (16 * ROWB) + 64);
      bf16x8v b2 = *(const bf16x8v*)(smem + fr_b + fj * (16 * ROWB) + 128);
#pragma unroll
      for (int fi = 0; fi < 4; fi++) {
        f32x4v c = acc[fi][fj];
        c = __builtin_amdgcn_mfma_f32_16x16x32_bf16(af[fi][2], b0, c, 0, 0, 0);
        c = __builtin_amdgcn_mfma_f32_16x16x32_bf16(af[fi][1], b1, c, 0, 0, 0);
        c = __builtin_amdgcn_mfma_f32_16x16x32_bf16(af[fi][0], b2, c, 0, 0, 0);
        c = __builtin_amdgcn_mfma_f32_16x16x32_bf16(af[fi][1], b0, c, 0, 0, 0);
        c = __builtin_amdgcn_mfma_f32_16x16x32_bf16(af[fi][0], b1, c, 0, 0, 0);
        c = __builtin_amdgcn_mfma_f32_16x16x32_bf16(af[fi][0], b0, c, 0, 0, 0);
        acc[fi][fj] = c;
      }
    }
  }
#undef PS3_LOAD

#pragma unroll
  for (int fi = 0; fi < 4; fi++) {
    int row0 = i0 + wrow * 64 + fi * 16 + (lane >> 4) * 4;
#pragma unroll
    for (int fj = 0; fj < 4; fj++) {
      int col = j0 + wcol * 64 + fj * 16 + (lane & 15);
      if (col >= N) continue;
      float badd = (bias && z == 0) ? bias[col] : 0.0f;
      f32x4v v = acc[fi][fj];
#pragma unroll
      for (int rr = 0; rr < 4; rr++) {
        int row = row0 + rr;
        if (row < M) {
          float o = v[rr] + badd;
          if (res && z == 0) o += res[(size_t)row * ldres + col];
          if (VtOut && col >= 1024 && col < 1536) {
            int d = col - 1024;
            int bb = row / 196;
            int kk = row - bb * 196;
            int zz = bb * 8 + (d >> 6);
            VtOut[(size_t)zz * 14336 + (size_t)(d & 63) * 224 + kk] = o;
          } else {
            C[(size_t)row * ldc + col] = o;
          }
        }
      }
    }
  }
}

// ---------------------------------------------------------------------------
// On-the-fly bf16x3 MFMA GEMM (batched attention GEMMs) with T14 async-stage:
// load+split of next chunk issued before the MFMA phase (split VALU overlaps
// MFMA pipe per m114). Optional limb output.
// ---------------------------------------------------------------------------
__global__ __launch_bounds__(256, 3) void gemm_bf16x3_kernel(
    const float* __restrict__ A, const float* __restrict__ B,
    float* __restrict__ C, const float* __restrict__ bias,
    const float* __restrict__ res,
    int M, int N, int K, int lda, int ldb, int ldc,
    int zInner, long long aOuter, long long aInner,
    long long bOuter, long long bInner,
    long long cOuter, long long cInner,
    unsigned short* __restrict__ Cl, long long clPlane)
{
  int z = blockIdx.z;
  int zo = z / zInner, zi = z % zInner;
  A += zo * aOuter + zi * aInner;
  B += zo * bOuter + zi * bInner;
  long long coff = zo * cOuter + zi * cInner;
  if (C) C += coff;
  if (Cl) Cl += coff;

  __shared__ __align__(16) unsigned char smem[2 * ATILE];  // 53248 B

  int tid = threadIdx.x;
  int lane = tid & 63, w = tid >> 6;
  int wrow = w >> 1, wcol = w & 1;
  int i0 = blockIdx.x * 128, j0 = blockIdx.y * 128;

  int srow = tid >> 1;
  int skh  = tid & 1;
  int arow = i0 + srow; if (arow > M - 1) arow = M - 1;
  int brow = j0 + srow; if (brow > N - 1) brow = N - 1;
  const float* aptr = A + (size_t)arow * lda + skh * 16;
  const float* bptr = B + (size_t)brow * ldb + skh * 16;
  unsigned swoff = (unsigned)srow * ROWB + (unsigned)skh * 32;

  f32x4v acc[4][4];
#pragma unroll
  for (int fi = 0; fi < 4; fi++)
#pragma unroll
    for (int fj = 0; fj < 4; fj++) acc[fi][fj] = (f32x4v){0.f, 0.f, 0.f, 0.f};

  unsigned fr_a = (unsigned)(wrow * 64 + (lane & 15)) * ROWB + (unsigned)(lane >> 4) * 16;
  unsigned fr_b = (unsigned)(wcol * 64 + (lane & 15)) * ROWB + (unsigned)(lane >> 4) * 16 + ATILE;

  bf16x8v pa0[3], pa1[3], pb0[3], pb1[3];   // packed limbs, persist to write
#define BF3_LOADSPLIT(K0)                                                 \
  { float av[16], bv[16];                                                 \
    { const float4 q0 = *(const float4*)(aptr + (K0));                    \
      const float4 q1 = *(const float4*)(aptr + (K0) + 4);                \
      const float4 q2 = *(const float4*)(aptr + (K0) + 8);                \
      const float4 q3 = *(const float4*)(aptr + (K0) + 12);               \
      av[0]=q0.x; av[1]=q0.y; av[2]=q0.z; av[3]=q0.w;                     \
      av[4]=q1.x; av[5]=q1.y; av[6]=q1.z; av[7]=q1.w;                     \
      av[8]=q2.x; av[9]=q2.y; av[10]=q2.z; av[11]=q2.w;                   \
      av[12]=q3.x; av[13]=q3.y; av[14]=q3.z; av[15]=q3.w;                 \
      const float4 r0 = *(const float4*)(bptr + (K0));                    \
      const float4 r1 = *(const float4*)(bptr + (K0) + 4);                \
      const float4 r2 = *(const float4*)(bptr + (K0) + 8);                \
      const float4 r3 = *(const float4*)(bptr + (K0) + 12);               \
      bv[0]=r0.x; bv[1]=r0.y; bv[2]=r0.z; bv[3]=r0.w;                     \
      bv[4]=r1.x; bv[5]=r1.y; bv[6]=r1.z; bv[7]=r1.w;                     \
      bv[8]=r2.x; bv[9]=r2.y; bv[10]=r2.z; bv[11]=r2.w;                   \
      bv[12]=r3.x; bv[13]=r3.y; bv[14]=r3.z; bv[15]=r3.w; }               \
    unsigned short ha[3][16], hb[3][16];                                  \
    _Pragma("unroll")                                                     \
    for (int e = 0; e < 16; e++) {                                        \
      split3_1(av[e], ha[0][e], ha[1][e], ha[2][e]);                      \
      split3_1(bv[e], hb[0][e], hb[1][e], hb[2][e]);                      \
    }                                                                     \
    _Pragma("unroll")                                                     \
    for (int s = 0; s < 3; s++) {                                         \
      _Pragma("unroll")                                                   \
      for (int e = 0; e < 8; e++) {                                       \
        pa0[s][e] = (short)ha[s][e]; pa1[s][e] = (short)ha[s][8 + e];     \
        pb0[s][e] = (short)hb[s][e]; pb1[s][e] = (short)hb[s][8 + e];     \
      }                                                                   \
    } }

  BF3_LOADSPLIT(0);
  for (int k0 = 0; k0 < K; k0 += GBK) {
    __syncthreads();
#pragma unroll
    for (int s = 0; s < 3; s++) {
      *(bf16x8v*)(smem + swoff + s * 64)              = pa0[s];
      *(bf16x8v*)(smem + swoff + s * 64 + 16)         = pa1[s];
      *(bf16x8v*)(smem + ATILE + swoff + s * 64)      = pb0[s];
      *(bf16x8v*)(smem + ATILE + swoff + s * 64 + 16) = pb1[s];
    }
    __syncthreads();

    if (k0 + GBK < K) { BF3_LOADSPLIT(k0 + GBK); }   // overlaps MFMA

    bf16x8v af[4][3];
#pragma unroll
    for (int fi = 0; fi < 4; fi++)
#pragma unroll
      for (int s = 0; s < 3; s++)
        af[fi][s] = *(const bf16x8v*)(smem + fr_a + fi * (16 * ROWB) + s * 64);

#pragma unroll
    for (int fj = 0; fj < 4; fj++) {
      bf16x8v b0 = *(const bf16x8v*)(smem + fr_b + fj * (16 * ROWB));
      bf16x8v b1 = *(const bf16x8v*)(smem + fr_b + fj * (16 * ROWB) + 64);
      bf16x8v b2 = *(const bf16x8v*)(smem + fr_b + fj * (16 * ROWB) + 128);
#pragma unroll
      for (int fi = 0; fi < 4; fi++) {
        f32x4v c = acc[fi][fj];
        c = __builtin_amdgcn_mfma_f32_16x16x32_bf16(af[fi][2], b0, c, 0, 0, 0);
        c = __builtin_amdgcn_mfma_f32_16x16x32_bf16(af[fi][1], b1, c, 0, 0, 0);
        c = __builtin_amdgcn_mfma_f32_16x16x32_bf16(af[fi][0], b2, c, 0, 0, 0);
        c = __builtin_amdgcn_mfma_f32_16x16x32_bf16(af[fi][1], b0, c, 0, 0, 0);
        c = __builtin_amdgcn_mfma_f32_16x16x32_bf16(af[fi][0], b1, c, 0, 0, 0);
        c = __builtin_amdgcn_mfma_f32_16x16x32_bf16(af[fi][0], b0, c, 0, 0, 0);
        acc[fi][fj] = c;
      }
    }
  }
#undef BF3_LOADSPLIT

#pragma unroll
  for (int fi = 0; fi < 4; fi++) {
    int row0 = i0 + wrow * 64 + fi * 16 + (lane >> 4) * 4;
#pragma unroll
    for (int fj = 0; fj < 4; fj++) {
      int col = j0 + wcol * 64 + fj * 16 + (lane & 15);
      if (col >= N) continue;
      float badd = bias ? bias[col] : 0.0f;
      f32x4v v = acc[fi][fj];
#pragma unroll
      for (int rr = 0; rr < 4; rr++) {
        int row = row0 + rr;
        if (row < M) {
          float o = v[rr] + badd;
          if (res) o += res[(size_t)row * ldc + col];
          size_t idx = (size_t)row * ldc + col;
          if (Cl) {
            unsigned short l0, l1, l2;
            split3_1(o, l0, l1, l2);
            Cl[idx] = l0; Cl[idx + clPlane] = l1; Cl[idx + 2 * clPlane] = l2;
          } else {
            C[idx] = o;
          }
        }
      }
    }
  }
}

// In-place row softmax of scaled scores: rows of length 196, scale 1/sqrt(64).
__global__ __launch_bounds__(256) void softmax_kernel(float* __restrict__ S)
{
  int row = blockIdx.x * 4 + (threadIdx.x >> 6);
  int lane = threadIdx.x & 63;
  float* sr = S + (size_t)row * 196;
  double v[4];
#pragma unroll
  for (int t = 0; t < 4; t++) {
    int j = lane + 64 * t;
    v[t] = (j < 196) ? (double)sr[j] * 0.125 : -1e300;
  }
  double mx = fmax(fmax(v[0], v[1]), fmax(v[2], v[3]));
#pragma unroll
  for (int off = 1; off < 64; off <<= 1) mx = fmax(mx, __shfl_xor(mx, off));
  double e[4]; double s = 0.0;
#pragma unroll
  for (int t = 0; t < 4; t++) {
    int j = lane + 64 * t;
    e[t] = (j < 196) ? exp(v[t] - mx) : 0.0;
    s += e[t];
  }
#pragma unroll
  for (int off = 1; off < 64; off <<= 1) s += __shfl_xor(s, off);
  double inv = 1.0 / s;
#pragma unroll
  for (int t = 0; t < 4; t++) {
    int j = lane + 64 * t;
    if (j < 196) sr[j] = (float)(e[t] * inv);
  }
}

// ---------------------------------------------------------------------------
// Fused LayerNorm (ddof=0, eps=1e-5) + exact GELU + w2 projection.
// h1 arrives as 4 split-K partials (fp64-summed here).
// ---------------------------------------------------------------------------
__global__ __launch_bounds__(256) void lnw2_kernel(
    const float* __restrict__ H, const float* __restrict__ g,
    const float* __restrict__ bb, const float* __restrict__ W2,
    const float* __restrict__ B2, float* __restrict__ Qp)
{
  int row = blockIdx.x;
  const float* hr = H + (size_t)row * 512;
  int tid = threadIdx.x, lane = tid & 63, wv = tid >> 6;
  __shared__ double red[8];
  __shared__ float y[512];
  double x0 = (double)hr[tid]       + (double)hr[tid + 1605632]
            + (double)hr[tid + 3211264] + (double)hr[tid + 4816896];
  double x1 = (double)hr[tid + 256] + (double)hr[tid + 256 + 1605632]
            + (double)hr[tid + 256 + 3211264] + (double)hr[tid + 256 + 4816896];
  double s = x0 + x1;
#pragma unroll
  for (int off = 1; off < 64; off <<= 1) s += __shfl_xor(s, off);
  if (lane == 0) red[wv] = s;
  __syncthreads();
  double mu = (red[0] + red[1] + red[2] + red[3]) * (1.0 / 512.0);
  double d0 = x0 - mu, d1 = x1 - mu;
  double q = d0 * d0 + d1 * d1;
#pragma unroll
  for (int off = 1; off < 64; off <<= 1) q += __shfl_xor(q, off);
  if (lane == 0) red[4 + wv] = q;
  __syncthreads();
  double var = (red[4] + red[5] + red[6] + red[7]) * (1.0 / 512.0);
  double inv = 1.0 / sqrt(var + 1e-5);
  double y0 = d0 * inv * (double)g[tid]       + (double)bb[tid];
  double y1 = d1 * inv * (double)g[tid + 256] + (double)bb[tid + 256];
  const double ISQRT2 = 0.70710678118654752440;
  double z0 = 0.5 * y0 * (1.0 + erf(y0 * ISQRT2));
  double z1 = 0.5 * y1 * (1.0 + erf(y1 * ISQRT2));
  y[tid] = (float)z0;
  y[tid + 256] = (float)z1;
  __syncthreads();

#pragma unroll 1
  for (int t = 0; t < 5; t++) {
    int m = wv * 5 + t;
    const float* wr = W2 + (size_t)m * 512;
    double acc = 0.0;
#pragma unroll
    for (int sE = 0; sE < 8; sE++) {
      int j = lane + 64 * sE;
      acc += (double)y[j] * (double)wr[j];
    }
#pragma unroll
    for (int off = 1; off < 64; off <<= 1) acc += __shfl_xor(acc, off);
    if (lane == 0) Qp[(size_t)row * 20 + m] = (float)(acc + (double)B2[m]);
  }
}

// ---------------------------------------------------------------------------
// topk selection v6: two tasks/wave with guarded QUATERNARY search (3
// midpoints per iteration -> serial chain ~halved vs binary), 32-bit prefix
// keys, min/max seeding, count==51 early exit; prefix-tie boundary resolved
// exactly by (low-32 desc, d asc). fp32 finish.
// ---------------------------------------------------------------------------
__device__ __forceinline__ void topk_finish32(
    const unsigned* uh, const unsigned* ul, const float* apf,
    unsigned thrh, bool exact, float qp, int g,
    unsigned long long* __restrict__ masks, float* __restrict__ qif, int lane)
{
  const int KSEL = 51;
  bool sel[8];
  if (exact) {
#pragma unroll
    for (int s = 0; s < 8; s++) sel[s] = (uh[s] >= thrh);
  } else {
    int cg = 0;
#pragma unroll
    for (int s = 0; s < 8; s++) {
      sel[s] = (uh[s] > thrh);
      cg += (int)__popcll(__ballot(sel[s]));
    }
    int need = KSEL - cg;
    bool tk[8];
#pragma unroll
    for (int s = 0; s < 8; s++) tk[s] = false;
    while (need > 0) {
      unsigned long long bk = 0ULL;
#pragma unroll
      for (int s = 0; s < 8; s++) {
        if (uh[s] == thrh && !tk[s]) {
          unsigned long long key = (1ULL << 41)
                                 | ((unsigned long long)ul[s] << 9)
                                 | ((unsigned long long)(7 - s) << 6)
                                 | (unsigned long long)(63 - lane);
          bk = key > bk ? key : bk;
        }
      }
#pragma unroll
      for (int off = 1; off < 64; off <<= 1) {
        unsigned long long ob = __shfl_xor(bk, off);
        bk = ob > bk ? ob : bk;
      }
      if ((int)(63 - (bk & 63ULL)) == lane) {
        int wsI = 7 - (int)((bk >> 6) & 7ULL);
        sel[wsI] = true;
        tk[wsI] = true;
      }
      need--;
    }
  }

  float ss = 0.f;
  unsigned long long selb[8];
#pragma unroll
  for (int s = 0; s < 8; s++) {
    selb[s] = __ballot((int)sel[s]);
    if (sel[s]) ss += apf[s] * apf[s];
  }
#pragma unroll
  for (int off = 1; off < 64; off <<= 1) ss += __shfl_xor(ss, off);
  float nrm = fabsf(qp) * sqrtf(ss);
  float qid = qp / fmaxf(nrm, 1e-6f);
  if (lane == 0) {
    qif[g] = qid;
#pragma unroll
    for (int s = 0; s < 8; s++) masks[(size_t)g * 8 + s] = selb[s];
  }
}

// one guarded quaternary step for a task; returns via refs
__device__ __forceinline__ void quat_step(
    const unsigned* uh, unsigned& lo, unsigned& hi, bool& ex, bool& dn)
{
  const int KSEL = 51;
  unsigned d = hi - lo;
  unsigned m1 = lo + (d >> 2);
  unsigned m2 = lo + (d >> 1);
  unsigned m3 = lo + (d - (d >> 2));
  int c1 = 0, c2 = 0, c3 = 0;
#pragma unroll
  for (int s = 0; s < 8; s++) {
    c1 += (int)__popcll(__ballot(uh[s] >= m1));
    c2 += (int)__popcll(__ballot(uh[s] >= m2));
    c3 += (int)__popcll(__ballot(uh[s] >= m3));
  }
  if (c3 >= KSEL)      { lo = m3;           if (c3 == KSEL) { ex = true; dn = true; } }
  else if (c2 >= KSEL) { lo = m2; hi = m3;  if (c2 == KSEL) { ex = true; dn = true; } }
  else if (c1 >= KSEL) { lo = m1; hi = m2;  if (c1 == KSEL) { ex = true; dn = true; } }
  else                 { hi = m1; }
  dn = dn || (hi - lo <= 1u);
}

__global__ __launch_bounds__(256) void topk_select_kernel(
    const float* __restrict__ F, const float* __restrict__ T,
    const float* __restrict__ Qp, unsigned long long* __restrict__ masks,
    float* __restrict__ qif)
{
  int wid = blockIdx.x * 4 + (threadIdx.x >> 6);
  int lane = threadIdx.x & 63;
  int g0 = wid * 2;                 // two tasks, same bn (20 % 2 == 0)
  int bn = g0 / 20, m0 = g0 - bn * 20;
  const float* Frow = F + (size_t)bn * 512;
  const float* T0r = T + (size_t)m0 * 512;
  const float* T1r = T0r + 512;

  unsigned uh0[8], ul0[8], uh1[8], ul1[8];
  float ap0[8], ap1[8];
#pragma unroll
  for (int s = 0; s < 8; s++) {
    double fd = (double)Frow[lane + 64 * s];
    double p0 = fd * (double)T0r[lane + 64 * s];   // exact in fp64
    double p1 = fd * (double)T1r[lane + 64 * s];
    unsigned long long u0 =
        (unsigned long long)__double_as_longlong(p0) & 0x7fffffffffffffffULL;
    unsigned long long u1 =
        (unsigned long long)__double_as_longlong(p1) & 0x7fffffffffffffffULL;
    uh0[s] = (unsigned)(u0 >> 32); ul0[s] = (unsigned)u0;
    uh1[s] = (unsigned)(u1 >> 32); ul1[s] = (unsigned)u1;
    ap0[s] = (float)fabs(p0); ap1[s] = (float)fabs(p1);
  }

  unsigned mx0 = 0u, mn0 = 0xffffffffu, mx1 = 0u, mn1 = 0xffffffffu;
#pragma unroll
  for (int s = 0; s < 8; s++) {
    mx0 = uh0[s] > mx0 ? uh0[s] : mx0;  mn0 = uh0[s] < mn0 ? uh0[s] : mn0;
    mx1 = uh1[s] > mx1 ? uh1[s] : mx1;  mn1 = uh1[s] < mn1 ? uh1[s] : mn1;
  }
#pragma unroll
  for (int off = 1; off < 64; off <<= 1) {
    unsigned a = __shfl_xor(mx0, off); mx0 = a > mx0 ? a : mx0;
    unsigned b = __shfl_xor(mn0, off); mn0 = b < mn0 ? b : mn0;
    unsigned c = __shfl_xor(mx1, off); mx1 = c > mx1 ? c : mx1;
    unsigned d = __shfl_xor(mn1, off); mn1 = d < mn1 ? d : mn1;
  }

  unsigned lo0 = mn0, hi0 = mx0 + 1u, lo1 = mn1, hi1 = mx1 + 1u;
  bool ex0 = false, ex1 = false;
  bool dn0 = (hi0 - lo0 <= 1u), dn1 = (hi1 - lo1 <= 1u);
  while (!(dn0 && dn1)) {
    if (!dn0) quat_step(uh0, lo0, hi0, ex0, dn0);   // wave-uniform guards
    if (!dn1) quat_step(uh1, lo1, hi1, ex1, dn1);
  }
  topk_finish32(uh0, ul0, ap0, lo0, ex0, Qp[g0],     g0,     masks, qif, lane);
  topk_finish32(uh1, ul1, ap1, lo1, ex1, Qp[g0 + 1], g0 + 1, masks, qif, lane);
}

// ---------------------------------------------------------------------------
// topk writeout: 2 blocks per bn (one 256-d half each) -> more block-level
// parallelism, half the syncthreads. LDS value tile -> coalesced float4.
// ---------------------------------------------------------------------------
__global__ __launch_bounds__(256) void topk_write_kernel(
    const float* __restrict__ F, const float* __restrict__ T,
    const unsigned long long* __restrict__ masks,
    const float* __restrict__ qif, float* __restrict__ out)
{
  int bid = blockIdx.x;
  int bn = bid >> 1, half = bid & 1;
  int tid = threadIdx.x;
  __shared__ unsigned long long mw[20][8];
  __shared__ float qf[20];
  __shared__ float vt[256][21];   // [d_local][m], stride 21: conflict-free
  if (tid < 160) ((unsigned long long*)mw)[tid] = masks[(size_t)bn * 160 + tid];
  if (tid < 20) qf[tid] = qif[(size_t)bn * 20 + tid];
  const float* Frow = F + (size_t)bn * 512;
  float* orow = out + (size_t)bn * 10240;
  __syncthreads();

  int d = half * 256 + tid;
  float fd = Frow[d];
  int dw = d >> 6, db = d & 63;
#pragma unroll
  for (int m = 0; m < 20; m++) {
    bool sel = (mw[m][dw] >> db) & 1ULL;
    float tv = T[(size_t)m * 512 + d];
    vt[tid][m] = sel ? fd * tv * qf[m] : 0.0f;
  }
  __syncthreads();
#pragma unroll
  for (int k = 0; k < 5; k++) {
    int flat = (k * 256 + tid) * 4;     // element within half [0,5120)
    float v[4];
#pragma unroll
    for (int e = 0; e < 4; e++) {
      int fe = flat + e;
      int dl = fe / 20;
      int mm = fe - dl * 20;
      v[e] = vt[dl][mm];
    }
    float4 o = {v[0], v[1], v[2], v[3]};
    *(float4*)&orow[half * 5120 + flat] = o;
  }
}

extern "C" void kernel_launch(void* const* d_in, const int* in_sizes, int n_in,
                              void* d_out, int out_size, void* d_ws, size_t ws_size,
                              hipStream_t stream) {
  const float* F    = (const float*)d_in[0];   // [3136,512]
  const float* Wqkv = (const float*)d_in[1];   // [1536,512]
  const float* bqkv = (const float*)d_in[2];   // [1536]
  const float* Wo   = (const float*)d_in[3];   // [512,512]
  const float* bo   = (const float*)d_in[4];   // [512]
  const float* W1   = (const float*)d_in[5];   // [512,512]
  const float* b1   = (const float*)d_in[6];   // [512]
  const float* lng  = (const float*)d_in[7];   // [512]
  const float* lnb  = (const float*)d_in[8];   // [512]
  const float* W2   = (const float*)d_in[9];   // [20,512]
  const float* b2   = (const float*)d_in[10];  // [20]
  const float* Tm   = (const float*)d_in[11];  // [20,512]
  float* out = (float*)d_out;

  float* ws = (float*)d_ws;
  // Dedicated regions (R11/R14-proven layout):
  float* qkvw   = ws;                          // [3136,2048] = 6,422,528
  float* scores = ws + 6422528;                // 4,917,248
  float* Vt     = ws + 11339776;               // 128*64*224 = 1,835,008
  float* h1p    = ws + 13174784;               // 4 x 1,605,632 = 6,422,528
  float* Qp     = ws + 19597312;               //    62,720
  float* bcomb  = ws + 19660032;               //       512
  float* biasAll= ws + 19660544;               //     2,048
  unsigned long long* masks = (unsigned long long*)(ws + 19662592);  // 1,003,520 fl
  float* qifb   = ws + 20666112;               //    62,720
  unsigned short* Fs    = (unsigned short*)(ws + 20728832);  // 2,408,448 fl
  unsigned short* Walls = (unsigned short*)(ws + 23137280);  // 1,572,864 fl
  unsigned short* Wcs   = (unsigned short*)(ws + 24710144);  //   393,216 fl
  unsigned short* Omgs  = (unsigned short*)(ws + 25103360);  // 2,408,448 fl
  dim3 blk(256);

  // 1) prep: limb splits (F, Wqkv+W1 -> Walls), Wc = W1@Wo -> limbs,
  //    Vt pad zero, bcomb, biasAll
  prep_kernel<<<dim3(1474), blk, 0, stream>>>(
      F, Fs, Wqkv, W1, Walls, Wo, Wcs, Vt, bo, b1, bcomb, bqkv, biasAll);

  // 2) qkvw = F @ [Wqkv;W1]^T + biasAll      [3136,2048]  (T14 + XCD swizzle)
  //    cols [0,1024): Q,K -> qkvw; [1024,1536): V -> Vt transposed;
  //    [1536,2048): F@W1^T -> qkvw (res for h1)
  gemm_ps3_kernel<<<dim3(25, 16, 1), blk, 0, stream>>>(
      Fs, Walls, qkvw, biasAll, nullptr,
      3136, 2048, 2048, 0, 1605632LL, 1048576LL, 512, 0LL, Vt, 1);

  // 3) scores[b,h] = Q[b,h] @ K[b,h]^T       [196,196] x 128  (on-the-fly)
  gemm_bf16x3_kernel<<<dim3(2, 2, 128), blk, 0, stream>>>(
      qkvw, qkvw + 512, scores, nullptr, nullptr,
      196, 196, 64, 2048, 2048, 196,
      8, 196LL * 2048, 64, 196LL * 2048, 64, 8LL * 38416, 38416,
      nullptr, 0);

  // 4) softmax rows (scale 0.125 inside)
  softmax_kernel<<<dim3(6272), blk, 0, stream>>>(scores);

  // 5) O[b,h] = P[b,h] @ Vt[b,h]^T -> Omg LIMBS directly
  gemm_bf16x3_kernel<<<dim3(2, 1, 128), blk, 0, stream>>>(
      scores, Vt, nullptr, nullptr, nullptr,
      196, 64, 196, 196, 224, 512,
      8, 8LL * 38416, 38416, 8LL * 14336, 14336, 100352, 64,
      Omgs, 1605632LL);

  // 6) h1 = Omg @ Wc^T + FW1 + bcomb, split-K x4 -> 4 partials
  gemm_ps3_kernel<<<dim3(25, 4, 4), blk, 0, stream>>>(
      Omgs, Wcs, h1p, bcomb, qkvw + 1536,
      3136, 512, 512, 2048, 1605632LL, 262144LL, 128, 1605632LL, nullptr, 0);

  // 7) fused LayerNorm + exact GELU + w2 -> Qp  (sums 4 partials)
  lnw2_kernel<<<dim3(3136), blk, 0, stream>>>(h1p, lng, lnb, W2, b2, Qp);

  // 8) selection: 2 tasks/wave, guarded quaternary search
  topk_select_kernel<<<dim3(7840), blk, 0, stream>>>(F, Tm, Qp, masks, qifb);

  // 9) streaming writeout of [B,N,D,M], 2 blocks per bn
  topk_write_kernel<<<dim3(6272), blk, 0, stream>>>(F, Tm, masks, qifb, out);
}

// Round 16
// 307.500 us; speedup vs baseline: 1.2619x; 1.2619x over previous
//
#include <hip/hip_runtime.h>
#include <cmath>

// ---------------------------------------------------------------------------
// Problem constants: B=16, N=196, D=512, M=20, H=8, hd=64, k=51
//   tokens = 3136, 3D = 1536
// Algebra: h1 = Omg@(W1*Wo)^T + F@W1^T + (W1*bo + b1)  [Fenh eliminated]
// R14 GEMMs restored EXACTLY (R15's T14 prefetch + launch_bounds(256,3)
// caused VGPR-cap scratch spills: VGPR 84 < needed, WRITE_SIZE 184MB of
// spill traffic, 2x slowdown). Kept from R15: quaternary select, 2-block
// write (unimplicated; measured this round vs R14's 314us).
// ---------------------------------------------------------------------------

typedef __attribute__((ext_vector_type(8))) short bf16x8v;
typedef __attribute__((ext_vector_type(4))) float f32x4v;

__device__ __forceinline__ unsigned short f2bf_rne(float x) {
  unsigned u = __float_as_uint(x);
  u += 0x7fffu + ((u >> 16) & 1u);   // round-to-nearest-even
  return (unsigned short)(u >> 16);
}
__device__ __forceinline__ float bf2f(unsigned short h) {
  return __uint_as_float(((unsigned)h) << 16);
}
__device__ __forceinline__ void split3_1(float x,
    unsigned short& s0, unsigned short& s1, unsigned short& s2) {
  s0 = f2bf_rne(x); float r1 = x - bf2f(s0);
  s1 = f2bf_rne(r1); float r2 = r1 - bf2f(s1);
  s2 = f2bf_rne(r2);
}

// ---------------------------------------------------------------------------
// prep mega-kernel (unchanged).
// ---------------------------------------------------------------------------
__global__ __launch_bounds__(256) void prep_kernel(
    const float* __restrict__ F, unsigned short* __restrict__ Fs,
    const float* __restrict__ Wqkv, const float* __restrict__ W1,
    unsigned short* __restrict__ Walls,
    const float* __restrict__ Wo, unsigned short* __restrict__ Wcs,
    float* __restrict__ Vt,
    const float* __restrict__ bo, const float* __restrict__ b1,
    float* __restrict__ bcomb,
    const float* __restrict__ bqkv, float* __restrict__ biasAll)
{
  int b = blockIdx.x;
  int tid = threadIdx.x;

  if (b < 1296) {  // ---- splits ----
    const float* X; unsigned short* O; long long i8, pstride;
    if (b < 784)       { X = F;    O = Fs;              pstride = 1605632; i8 = (long long)b * 256 + tid; }
    else if (b < 1168) { X = Wqkv; O = Walls;           pstride = 1048576; i8 = (long long)(b - 784) * 256 + tid; }
    else               { X = W1;   O = Walls + 786432;  pstride = 1048576; i8 = (long long)(b - 1168) * 256 + tid; }
    const float4 aa = *(const float4*)(X + i8 * 8);
    const float4 bb = *(const float4*)(X + i8 * 8 + 4);
    float xs[8] = {aa.x, aa.y, aa.z, aa.w, bb.x, bb.y, bb.z, bb.w};
    bf16x8v o0, o1, o2;
#pragma unroll
    for (int e = 0; e < 8; e++) {
      unsigned short s0, s1, s2;
      split3_1(xs[e], s0, s1, s2);
      o0[e] = (short)s0; o1[e] = (short)s1; o2[e] = (short)s2;
    }
    *(bf16x8v*)(O + i8 * 8)               = o0;
    *(bf16x8v*)(O + pstride + i8 * 8)     = o1;
    *(bf16x8v*)(O + 2 * pstride + i8 * 8) = o2;
    return;
  }

  if (b < 1360) {  // ---- Wc = W1 @ Wo, 64x64 tile, limb output ----
    __shared__ __align__(16) float As[16][68];
    __shared__ __align__(16) float Bs[16][68];
    int local = b - 1296;
    int i0 = (local >> 3) * 64, j0 = (local & 7) * 64;
    int tx = tid & 15, ty = tid >> 4;
    double acc[4][4];
#pragma unroll
    for (int i = 0; i < 4; i++)
#pragma unroll
      for (int j = 0; j < 4; j++) acc[i][j] = 0.0;
    for (int k0 = 0; k0 < 512; k0 += 16) {
#pragma unroll
      for (int rr = 0; rr < 4; rr++) {
        int r = ty + 16 * rr;
        As[tx][r] = W1[(size_t)(i0 + r) * 512 + k0 + tx];
      }
      {
        int j = tid & 63, c0 = (tid >> 6) * 4;
#pragma unroll
        for (int cc = 0; cc < 4; cc++) {
          int c = c0 + cc;
          Bs[c][j] = Wo[(size_t)(k0 + c) * 512 + j0 + j];
        }
      }
      __syncthreads();
      float cf[4][4];
#pragma unroll
      for (int i = 0; i < 4; i++)
#pragma unroll
        for (int j = 0; j < 4; j++) cf[i][j] = 0.0f;
#pragma unroll
      for (int kk = 0; kk < 16; kk++) {
        float4 a4 = *(const float4*)&As[kk][ty * 4];
        float4 b4 = *(const float4*)&Bs[kk][tx * 4];
        float av[4] = {a4.x, a4.y, a4.z, a4.w};
        float bv[4] = {b4.x, b4.y, b4.z, b4.w};
#pragma unroll
        for (int i = 0; i < 4; i++)
#pragma unroll
          for (int j = 0; j < 4; j++) cf[i][j] = fmaf(av[i], bv[j], cf[i][j]);
      }
#pragma unroll
      for (int i = 0; i < 4; i++)
#pragma unroll
        for (int j = 0; j < 4; j++) acc[i][j] += (double)cf[i][j];
      __syncthreads();
    }
#pragma unroll
    for (int i = 0; i < 4; i++) {
      int gi = i0 + ty * 4 + i;
#pragma unroll
      for (int j = 0; j < 4; j++) {
        int gj = j0 + tx * 4 + j;
        float o = (float)acc[i][j];
        unsigned short l0, l1, l2;
        split3_1(o, l0, l1, l2);
        size_t idx = (size_t)gi * 512 + gj;
        Wcs[idx] = l0; Wcs[idx + 262144] = l1; Wcs[idx + 524288] = l2;
      }
    }
    return;
  }

  if (b < 1472) {  // ---- zero Vt pad: 128 z x 64 d x 28 kk = 229376 ----
    long long p0 = (long long)(b - 1360) * 2048 + tid * 8;
#pragma unroll
    for (int e = 0; e < 8; e++) {
      long long pf = p0 + e;
      int z = (int)(pf / 1792);
      int r = (int)(pf - (long long)z * 1792);
      int d = r / 28, kk = r - d * 28;
      Vt[(size_t)z * 14336 + (size_t)d * 224 + 196 + kk] = 0.0f;
    }
    return;
  }

  if (b == 1472) {  // ---- bcomb ----
#pragma unroll
    for (int half = 0; half < 2; half++) {
      int n = tid + half * 256;
      const float* wr = W1 + (size_t)n * 512;
      double acc = 0.0;
      for (int k = 0; k < 512; k += 4) {
        float4 wv = *(const float4*)&wr[k];
        float4 bv = *(const float4*)&bo[k];
        acc += (double)wv.x * bv.x + (double)wv.y * bv.y +
               (double)wv.z * bv.z + (double)wv.w * bv.w;
      }
      bcomb[n] = (float)(acc + (double)b1[n]);
    }
    return;
  }

  // b == 1473: biasAll
#pragma unroll
  for (int e = 0; e < 8; e++) {
    int idx = tid * 8 + e;
    biasAll[idx] = (idx < 1536) ? bqkv[idx] : 0.0f;
  }
}

#define GBK 32
// Row-interleaved limb LDS layout: per row [s0 64B | s1 64B | s2 64B | 16B pad]
#define ROWB 208                 // bytes per row
#define ATILE (128 * ROWB)       // 26624 B per operand tile; total 53248 B

// ---------------------------------------------------------------------------
// Pre-split bf16x3 MFMA GEMM (R14 version — no prefetch, no reg cap).
// ---------------------------------------------------------------------------
__global__ __launch_bounds__(256) void gemm_ps3_kernel(
    const unsigned short* __restrict__ As, const unsigned short* __restrict__ Bs,
    float* __restrict__ C, const float* __restrict__ bias,
    const float* __restrict__ res,
    int M, int N, int ldc, int ldres,
    long long aPlane, long long bPlane,
    int kLen, long long cZStride,
    float* __restrict__ VtOut)
{
  __shared__ __align__(16) unsigned char smem[2 * ATILE];  // 53248 B -> 3 blk/CU

  int z = blockIdx.z;
  int kOff = z * kLen;
  C += (size_t)z * cZStride;

  int tid = threadIdx.x;
  int lane = tid & 63, w = tid >> 6;
  int wrow = w >> 1, wcol = w & 1;
  int i0 = blockIdx.x * 128, j0 = blockIdx.y * 128;

  int r = tid >> 1, hh = tid & 1;
  int arow = i0 + r; if (arow > M - 1) arow = M - 1;
  int brow = j0 + r; if (brow > N - 1) brow = N - 1;
  const unsigned short* ap = As + (size_t)arow * 512 + hh * 16 + kOff;
  const unsigned short* bp = Bs + (size_t)brow * 512 + hh * 16 + kOff;
  unsigned swoff = (unsigned)r * ROWB + (unsigned)hh * 32;

  f32x4v acc[4][4];
#pragma unroll
  for (int fi = 0; fi < 4; fi++)
#pragma unroll
    for (int fj = 0; fj < 4; fj++) acc[fi][fj] = (f32x4v){0.f, 0.f, 0.f, 0.f};

  unsigned fr_a = (unsigned)(wrow * 64 + (lane & 15)) * ROWB + (unsigned)(lane >> 4) * 16;
  unsigned fr_b = (unsigned)(wcol * 64 + (lane & 15)) * ROWB + (unsigned)(lane >> 4) * 16 + ATILE;

  for (int k0 = 0; k0 < kLen; k0 += GBK) {
    bf16x8v a0[3], a1[3], b0v[3], b1v[3];
#pragma unroll
    for (int s = 0; s < 3; s++) {
      a0[s]  = *(const bf16x8v*)(ap + s * aPlane + k0);
      a1[s]  = *(const bf16x8v*)(ap + s * aPlane + k0 + 8);
      b0v[s] = *(const bf16x8v*)(bp + s * bPlane + k0);
      b1v[s] = *(const bf16x8v*)(bp + s * bPlane + k0 + 8);
    }
    __syncthreads();  // previous chunk's frag reads complete
#pragma unroll
    for (int s = 0; s < 3; s++) {
      *(bf16x8v*)(smem + swoff + s * 64)              = a0[s];
      *(bf16x8v*)(smem + swoff + s * 64 + 16)         = a1[s];
      *(bf16x8v*)(smem + ATILE + swoff + s * 64)      = b0v[s];
      *(bf16x8v*)(smem + ATILE + swoff + s * 64 + 16) = b1v[s];
    }
    __syncthreads();

    bf16x8v af[4][3];
#pragma unroll
    for (int fi = 0; fi < 4; fi++)
#pragma unroll
      for (int s = 0; s < 3; s++)
        af[fi][s] = *(const bf16x8v*)(smem + fr_a + fi * (16 * ROWB) + s * 64);

#pragma unroll
    for (int fj = 0; fj < 4; fj++) {
      bf16x8v b0 = *(const bf16x8v*)(smem + fr_b + fj * (16 * ROWB));
      bf16x8v b1 = *(const bf16x8v*)(smem + fr_b + fj * (16 * ROWB) + 64);
      bf16x8v b2 = *(const bf16x8v*)(smem + fr_b + fj * (16 * ROWB) + 128);
#pragma unroll
      for (int fi = 0; fi < 4; fi++) {
        f32x4v c = acc[fi][fj];
        c = __builtin_amdgcn_mfma_f32_16x16x32_bf16(af[fi][2], b0, c, 0, 0, 0);
        c = __builtin_amdgcn_mfma_f32_16x16x32_bf16(af[fi][1], b1, c, 0, 0, 0);
        c = __builtin_amdgcn_mfma_f32_16x16x32_bf16(af[fi][0], b2, c, 0, 0, 0);
        c = __builtin_amdgcn_mfma_f32_16x16x32_bf16(af[fi][1], b0, c, 0, 0, 0);
        c = __builtin_amdgcn_mfma_f32_16x16x32_bf16(af[fi][0], b1, c, 0, 0, 0);
        c = __builtin_amdgcn_mfma_f32_16x16x32_bf16(af[fi][0], b0, c, 0, 0, 0);
        acc[fi][fj] = c;
      }
    }
  }

#pragma unroll
  for (int fi = 0; fi < 4; fi++) {
    int row0 = i0 + wrow * 64 + fi * 16 + (lane >> 4) * 4;
#pragma unroll
    for (int fj = 0; fj < 4; fj++) {
      int col = j0 + wcol * 64 + fj * 16 + (lane & 15);
      if (col >= N) continue;
      float badd = (bias && z == 0) ? bias[col] : 0.0f;
      f32x4v v = acc[fi][fj];
#pragma unroll
      for (int rr = 0; rr < 4; rr++) {
        int row = row0 + rr;
        if (row < M) {
          float o = v[rr] + badd;
          if (res && z == 0) o += res[(size_t)row * ldres + col];
          if (VtOut && col >= 1024 && col < 1536) {
            int d = col - 1024;
            int bb = row / 196;
            int kk = row - bb * 196;
            int zz = bb * 8 + (d >> 6);
            VtOut[(size_t)zz * 14336 + (size_t)(d & 63) * 224 + kk] = o;
          } else {
            C[(size_t)row * ldc + col] = o;
          }
        }
      }
    }
  }
}

// ---------------------------------------------------------------------------
// On-the-fly bf16x3 MFMA GEMM (R14 version). Optional limb output.
// ---------------------------------------------------------------------------
__global__ __launch_bounds__(256) void gemm_bf16x3_kernel(
    const float* __restrict__ A, const float* __restrict__ B,
    float* __restrict__ C, const float* __restrict__ bias,
    const float* __restrict__ res,
    int M, int N, int K, int lda, int ldb, int ldc,
    int zInner, long long aOuter, long long aInner,
    long long bOuter, long long bInner,
    long long cOuter, long long cInner,
    unsigned short* __restrict__ Cl, long long clPlane)
{
  int z = blockIdx.z;
  int zo = z / zInner, zi = z % zInner;
  A += zo * aOuter + zi * aInner;
  B += zo * bOuter + zi * bInner;
  long long coff = zo * cOuter + zi * cInner;
  if (C) C += coff;
  if (Cl) Cl += coff;

  __shared__ __align__(16) unsigned char smem[2 * ATILE];  // 53248 B

  int tid = threadIdx.x;
  int lane = tid & 63, w = tid >> 6;
  int wrow = w >> 1, wcol = w & 1;
  int i0 = blockIdx.x * 128, j0 = blockIdx.y * 128;

  int srow = tid >> 1;
  int skh  = tid & 1;
  int arow = i0 + srow; if (arow > M - 1) arow = M - 1;
  int brow = j0 + srow; if (brow > N - 1) brow = N - 1;
  const float* aptr = A + (size_t)arow * lda + skh * 16;
  const float* bptr = B + (size_t)brow * ldb + skh * 16;
  unsigned swoff = (unsigned)srow * ROWB + (unsigned)skh * 32;

  f32x4v acc[4][4];
#pragma unroll
  for (int fi = 0; fi < 4; fi++)
#pragma unroll
    for (int fj = 0; fj < 4; fj++) acc[fi][fj] = (f32x4v){0.f, 0.f, 0.f, 0.f};

  unsigned fr_a = (unsigned)(wrow * 64 + (lane & 15)) * ROWB + (unsigned)(lane >> 4) * 16;
  unsigned fr_b = (unsigned)(wcol * 64 + (lane & 15)) * ROWB + (unsigned)(lane >> 4) * 16 + ATILE;

  for (int k0 = 0; k0 < K; k0 += GBK) {
    float av[16], bv[16];
    {
      const float4 q0 = *(const float4*)(aptr + k0);
      const float4 q1 = *(const float4*)(aptr + k0 + 4);
      const float4 q2 = *(const float4*)(aptr + k0 + 8);
      const float4 q3 = *(const float4*)(aptr + k0 + 12);
      av[0]=q0.x; av[1]=q0.y; av[2]=q0.z; av[3]=q0.w;
      av[4]=q1.x; av[5]=q1.y; av[6]=q1.z; av[7]=q1.w;
      av[8]=q2.x; av[9]=q2.y; av[10]=q2.z; av[11]=q2.w;
      av[12]=q3.x; av[13]=q3.y; av[14]=q3.z; av[15]=q3.w;
      const float4 r0 = *(const float4*)(bptr + k0);
      const float4 r1 = *(const float4*)(bptr + k0 + 4);
      const float4 r2 = *(const float4*)(bptr + k0 + 8);
      const float4 r3 = *(const float4*)(bptr + k0 + 12);
      bv[0]=r0.x; bv[1]=r0.y; bv[2]=r0.z; bv[3]=r0.w;
      bv[4]=r1.x; bv[5]=r1.y; bv[6]=r1.z; bv[7]=r1.w;
      bv[8]=r2.x; bv[9]=r2.y; bv[10]=r2.z; bv[11]=r2.w;
      bv[12]=r3.x; bv[13]=r3.y; bv[14]=r3.z; bv[15]=r3.w;
    }
    unsigned short ha[3][16], hb[3][16];
#pragma unroll
    for (int e = 0; e < 16; e++) {
      split3_1(av[e], ha[0][e], ha[1][e], ha[2][e]);
      split3_1(bv[e], hb[0][e], hb[1][e], hb[2][e]);
    }
    __syncthreads();
#pragma unroll
    for (int s = 0; s < 3; s++) {
      bf16x8v v0, v1, w0, w1;
#pragma unroll
      for (int e = 0; e < 8; e++) {
        v0[e] = (short)ha[s][e]; v1[e] = (short)ha[s][8 + e];
        w0[e] = (short)hb[s][e]; w1[e] = (short)hb[s][8 + e];
      }
      *(bf16x8v*)(smem + swoff + s * 64)              = v0;
      *(bf16x8v*)(smem + swoff + s * 64 + 16)         = v1;
      *(bf16x8v*)(smem + ATILE + swoff + s * 64)      = w0;
      *(bf16x8v*)(smem + ATILE + swoff + s * 64 + 16) = w1;
    }
    __syncthreads();

    bf16x8v af[4][3];
#pragma unroll
    for (int fi = 0; fi < 4; fi++)
#pragma unroll
      for (int s = 0; s < 3; s++)
        af[fi][s] = *(const bf16x8v*)(smem + fr_a + fi * (16 * ROWB) + s * 64);

#pragma unroll
    for (int fj = 0; fj < 4; fj++) {
      bf16x8v b0 = *(const bf16x8v*)(smem + fr_b + fj * (16 * ROWB));
      bf16x8v b1 = *(const bf16x8v*)(smem + fr_b + fj * (16 * ROWB) + 64);
      bf16x8v b2 = *(const bf16x8v*)(smem + fr_b + fj * (16 * ROWB) + 128);
#pragma unroll
      for (int fi = 0; fi < 4; fi++) {
        f32x4v c = acc[fi][fj];
        c = __builtin_amdgcn_mfma_f32_16x16x32_bf16(af[fi][2], b0, c, 0, 0, 0);
        c = __builtin_amdgcn_mfma_f32_16x16x32_bf16(af[fi][1], b1, c, 0, 0, 0);
        c = __builtin_amdgcn_mfma_f32_16x16x32_bf16(af[fi][0], b2, c, 0, 0, 0);
        c = __builtin_amdgcn_mfma_f32_16x16x32_bf16(af[fi][1], b0, c, 0, 0, 0);
        c = __builtin_amdgcn_mfma_f32_16x16x32_bf16(af[fi][0], b1, c, 0, 0, 0);
        c = __builtin_amdgcn_mfma_f32_16x16x32_bf16(af[fi][0], b0, c, 0, 0, 0);
        acc[fi][fj] = c;
      }
    }
  }

#pragma unroll
  for (int fi = 0; fi < 4; fi++) {
    int row0 = i0 + wrow * 64 + fi * 16 + (lane >> 4) * 4;
#pragma unroll
    for (int fj = 0; fj < 4; fj++) {
      int col = j0 + wcol * 64 + fj * 16 + (lane & 15);
      if (col >= N) continue;
      float badd = bias ? bias[col] : 0.0f;
      f32x4v v = acc[fi][fj];
#pragma unroll
      for (int rr = 0; rr < 4; rr++) {
        int row = row0 + rr;
        if (row < M) {
          float o = v[rr] + badd;
          if (res) o += res[(size_t)row * ldc + col];
          size_t idx = (size_t)row * ldc + col;
          if (Cl) {
            unsigned short l0, l1, l2;
            split3_1(o, l0, l1, l2);
            Cl[idx] = l0; Cl[idx + clPlane] = l1; Cl[idx + 2 * clPlane] = l2;
          } else {
            C[idx] = o;
          }
        }
      }
    }
  }
}

// In-place row softmax of scaled scores: rows of length 196, scale 1/sqrt(64).
__global__ __launch_bounds__(256) void softmax_kernel(float* __restrict__ S)
{
  int row = blockIdx.x * 4 + (threadIdx.x >> 6);
  int lane = threadIdx.x & 63;
  float* sr = S + (size_t)row * 196;
  double v[4];
#pragma unroll
  for (int t = 0; t < 4; t++) {
    int j = lane + 64 * t;
    v[t] = (j < 196) ? (double)sr[j] * 0.125 : -1e300;
  }
  double mx = fmax(fmax(v[0], v[1]), fmax(v[2], v[3]));
#pragma unroll
  for (int off = 1; off < 64; off <<= 1) mx = fmax(mx, __shfl_xor(mx, off));
  double e[4]; double s = 0.0;
#pragma unroll
  for (int t = 0; t < 4; t++) {
    int j = lane + 64 * t;
    e[t] = (j < 196) ? exp(v[t] - mx) : 0.0;
    s += e[t];
  }
#pragma unroll
  for (int off = 1; off < 64; off <<= 1) s += __shfl_xor(s, off);
  double inv = 1.0 / s;
#pragma unroll
  for (int t = 0; t < 4; t++) {
    int j = lane + 64 * t;
    if (j < 196) sr[j] = (float)(e[t] * inv);
  }
}

// ---------------------------------------------------------------------------
// Fused LayerNorm (ddof=0, eps=1e-5) + exact GELU + w2 projection.
// h1 arrives as 4 split-K partials (fp64-summed here).
// ---------------------------------------------------------------------------
__global__ __launch_bounds__(256) void lnw2_kernel(
    const float* __restrict__ H, const float* __restrict__ g,
    const float* __restrict__ bb, const float* __restrict__ W2,
    const float* __restrict__ B2, float* __restrict__ Qp)
{
  int row = blockIdx.x;
  const float* hr = H + (size_t)row * 512;
  int tid = threadIdx.x, lane = tid & 63, wv = tid >> 6;
  __shared__ double red[8];
  __shared__ float y[512];
  double x0 = (double)hr[tid]       + (double)hr[tid + 1605632]
            + (double)hr[tid + 3211264] + (double)hr[tid + 4816896];
  double x1 = (double)hr[tid + 256] + (double)hr[tid + 256 + 1605632]
            + (double)hr[tid + 256 + 3211264] + (double)hr[tid + 256 + 4816896];
  double s = x0 + x1;
#pragma unroll
  for (int off = 1; off < 64; off <<= 1) s += __shfl_xor(s, off);
  if (lane == 0) red[wv] = s;
  __syncthreads();
  double mu = (red[0] + red[1] + red[2] + red[3]) * (1.0 / 512.0);
  double d0 = x0 - mu, d1 = x1 - mu;
  double q = d0 * d0 + d1 * d1;
#pragma unroll
  for (int off = 1; off < 64; off <<= 1) q += __shfl_xor(q, off);
  if (lane == 0) red[4 + wv] = q;
  __syncthreads();
  double var = (red[4] + red[5] + red[6] + red[7]) * (1.0 / 512.0);
  double inv = 1.0 / sqrt(var + 1e-5);
  double y0 = d0 * inv * (double)g[tid]       + (double)bb[tid];
  double y1 = d1 * inv * (double)g[tid + 256] + (double)bb[tid + 256];
  const double ISQRT2 = 0.70710678118654752440;
  double z0 = 0.5 * y0 * (1.0 + erf(y0 * ISQRT2));
  double z1 = 0.5 * y1 * (1.0 + erf(y1 * ISQRT2));
  y[tid] = (float)z0;
  y[tid + 256] = (float)z1;
  __syncthreads();

#pragma unroll 1
  for (int t = 0; t < 5; t++) {
    int m = wv * 5 + t;
    const float* wr = W2 + (size_t)m * 512;
    double acc = 0.0;
#pragma unroll
    for (int sE = 0; sE < 8; sE++) {
      int j = lane + 64 * sE;
      acc += (double)y[j] * (double)wr[j];
    }
#pragma unroll
    for (int off = 1; off < 64; off <<= 1) acc += __shfl_xor(acc, off);
    if (lane == 0) Qp[(size_t)row * 20 + m] = (float)(acc + (double)B2[m]);
  }
}

// ---------------------------------------------------------------------------
// topk selection: two tasks/wave, guarded QUATERNARY search (3 midpoints per
// iteration), 32-bit prefix keys, min/max seeding, count==51 early exit;
// prefix-tie boundary resolved exactly by (low-32 desc, d asc). fp32 finish.
// ---------------------------------------------------------------------------
__device__ __forceinline__ void topk_finish32(
    const unsigned* uh, const unsigned* ul, const float* apf,
    unsigned thrh, bool exact, float qp, int g,
    unsigned long long* __restrict__ masks, float* __restrict__ qif, int lane)
{
  const int KSEL = 51;
  bool sel[8];
  if (exact) {
#pragma unroll
    for (int s = 0; s < 8; s++) sel[s] = (uh[s] >= thrh);
  } else {
    int cg = 0;
#pragma unroll
    for (int s = 0; s < 8; s++) {
      sel[s] = (uh[s] > thrh);
      cg += (int)__popcll(__ballot(sel[s]));
    }
    int need = KSEL - cg;
    bool tk[8];
#pragma unroll
    for (int s = 0; s < 8; s++) tk[s] = false;
    while (need > 0) {
      unsigned long long bk = 0ULL;
#pragma unroll
      for (int s = 0; s < 8; s++) {
        if (uh[s] == thrh && !tk[s]) {
          unsigned long long key = (1ULL << 41)
                                 | ((unsigned long long)ul[s] << 9)
                                 | ((unsigned long long)(7 - s) << 6)
                                 | (unsigned long long)(63 - lane);
          bk = key > bk ? key : bk;
        }
      }
#pragma unroll
      for (int off = 1; off < 64; off <<= 1) {
        unsigned long long ob = __shfl_xor(bk, off);
        bk = ob > bk ? ob : bk;
      }
      if ((int)(63 - (bk & 63ULL)) == lane) {
        int wsI = 7 - (int)((bk >> 6) & 7ULL);
        sel[wsI] = true;
        tk[wsI] = true;
      }
      need--;
    }
  }

  float ss = 0.f;
  unsigned long long selb[8];
#pragma unroll
  for (int s = 0; s < 8; s++) {
    selb[s] = __ballot((int)sel[s]);
    if (sel[s]) ss += apf[s] * apf[s];
  }
#pragma unroll
  for (int off = 1; off < 64; off <<= 1) ss += __shfl_xor(ss, off);
  float nrm = fabsf(qp) * sqrtf(ss);
  float qid = qp / fmaxf(nrm, 1e-6f);
  if (lane == 0) {
    qif[g] = qid;
#pragma unroll
    for (int s = 0; s < 8; s++) masks[(size_t)g * 8 + s] = selb[s];
  }
}

// one guarded quaternary step for a task; returns via refs
__device__ __forceinline__ void quat_step(
    const unsigned* uh, unsigned& lo, unsigned& hi, bool& ex, bool& dn)
{
  const int KSEL = 51;
  unsigned d = hi - lo;
  unsigned m1 = lo + (d >> 2);
  unsigned m2 = lo + (d >> 1);
  unsigned m3 = lo + (d - (d >> 2));
  int c1 = 0, c2 = 0, c3 = 0;
#pragma unroll
  for (int s = 0; s < 8; s++) {
    c1 += (int)__popcll(__ballot(uh[s] >= m1));
    c2 += (int)__popcll(__ballot(uh[s] >= m2));
    c3 += (int)__popcll(__ballot(uh[s] >= m3));
  }
  if (c3 >= KSEL)      { lo = m3;           if (c3 == KSEL) { ex = true; dn = true; } }
  else if (c2 >= KSEL) { lo = m2; hi = m3;  if (c2 == KSEL) { ex = true; dn = true; } }
  else if (c1 >= KSEL) { lo = m1; hi = m2;  if (c1 == KSEL) { ex = true; dn = true; } }
  else                 { hi = m1; }
  dn = dn || (hi - lo <= 1u);
}

__global__ __launch_bounds__(256) void topk_select_kernel(
    const float* __restrict__ F, const float* __restrict__ T,
    const float* __restrict__ Qp, unsigned long long* __restrict__ masks,
    float* __restrict__ qif)
{
  int wid = blockIdx.x * 4 + (threadIdx.x >> 6);
  int lane = threadIdx.x & 63;
  int g0 = wid * 2;                 // two tasks, same bn (20 % 2 == 0)
  int bn = g0 / 20, m0 = g0 - bn * 20;
  const float* Frow = F + (size_t)bn * 512;
  const float* T0r = T + (size_t)m0 * 512;
  const float* T1r = T0r + 512;

  unsigned uh0[8], ul0[8], uh1[8], ul1[8];
  float ap0[8], ap1[8];
#pragma unroll
  for (int s = 0; s < 8; s++) {
    double fd = (double)Frow[lane + 64 * s];
    double p0 = fd * (double)T0r[lane + 64 * s];   // exact in fp64
    double p1 = fd * (double)T1r[lane + 64 * s];
    unsigned long long u0 =
        (unsigned long long)__double_as_longlong(p0) & 0x7fffffffffffffffULL;
    unsigned long long u1 =
        (unsigned long long)__double_as_longlong(p1) & 0x7fffffffffffffffULL;
    uh0[s] = (unsigned)(u0 >> 32); ul0[s] = (unsigned)u0;
    uh1[s] = (unsigned)(u1 >> 32); ul1[s] = (unsigned)u1;
    ap0[s] = (float)fabs(p0); ap1[s] = (float)fabs(p1);
  }

  unsigned mx0 = 0u, mn0 = 0xffffffffu, mx1 = 0u, mn1 = 0xffffffffu;
#pragma unroll
  for (int s = 0; s < 8; s++) {
    mx0 = uh0[s] > mx0 ? uh0[s] : mx0;  mn0 = uh0[s] < mn0 ? uh0[s] : mn0;
    mx1 = uh1[s] > mx1 ? uh1[s] : mx1;  mn1 = uh1[s] < mn1 ? uh1[s] : mn1;
  }
#pragma unroll
  for (int off = 1; off < 64; off <<= 1) {
    unsigned a = __shfl_xor(mx0, off); mx0 = a > mx0 ? a : mx0;
    unsigned b = __shfl_xor(mn0, off); mn0 = b < mn0 ? b : mn0;
    unsigned c = __shfl_xor(mx1, off); mx1 = c > mx1 ? c : mx1;
    unsigned d = __shfl_xor(mn1, off); mn1 = d < mn1 ? d : mn1;
  }

  unsigned lo0 = mn0, hi0 = mx0 + 1u, lo1 = mn1, hi1 = mx1 + 1u;
  bool ex0 = false, ex1 = false;
  bool dn0 = (hi0 - lo0 <= 1u), dn1 = (hi1 - lo1 <= 1u);
  while (!(dn0 && dn1)) {
    if (!dn0) quat_step(uh0, lo0, hi0, ex0, dn0);   // wave-uniform guards
    if (!dn1) quat_step(uh1, lo1, hi1, ex1, dn1);
  }
  topk_finish32(uh0, ul0, ap0, lo0, ex0, Qp[g0],     g0,     masks, qif, lane);
  topk_finish32(uh1, ul1, ap1, lo1, ex1, Qp[g0 + 1], g0 + 1, masks, qif, lane);
}

// ---------------------------------------------------------------------------
// topk writeout: 2 blocks per bn (one 256-d half each). LDS value tile ->
// coalesced float4 stores, 0 bank conflicts.
// ---------------------------------------------------------------------------
__global__ __launch_bounds__(256) void topk_write_kernel(
    const float* __restrict__ F, const float* __restrict__ T,
    const unsigned long long* __restrict__ masks,
    const float* __restrict__ qif, float* __restrict__ out)
{
  int bid = blockIdx.x;
  int bn = bid >> 1, half = bid & 1;
  int tid = threadIdx.x;
  __shared__ unsigned long long mw[20][8];
  __shared__ float qf[20];
  __shared__ float vt[256][21];   // [d_local][m], stride 21: conflict-free
  if (tid < 160) ((unsigned long long*)mw)[tid] = masks[(size_t)bn * 160 + tid];
  if (tid < 20) qf[tid] = qif[(size_t)bn * 20 + tid];
  const float* Frow = F + (size_t)bn * 512;
  float* orow = out + (size_t)bn * 10240;
  __syncthreads();

  int d = half * 256 + tid;
  float fd = Frow[d];
  int dw = d >> 6, db = d & 63;
#pragma unroll
  for (int m = 0; m < 20; m++) {
    bool sel = (mw[m][dw] >> db) & 1ULL;
    float tv = T[(size_t)m * 512 + d];
    vt[tid][m] = sel ? fd * tv * qf[m] : 0.0f;
  }
  __syncthreads();
#pragma unroll
  for (int k = 0; k < 5; k++) {
    int flat = (k * 256 + tid) * 4;     // element within half [0,5120)
    float v[4];
#pragma unroll
    for (int e = 0; e < 4; e++) {
      int fe = flat + e;
      int dl = fe / 20;
      int mm = fe - dl * 20;
      v[e] = vt[dl][mm];
    }
    float4 o = {v[0], v[1], v[2], v[3]};
    *(float4*)&orow[half * 5120 + flat] = o;
  }
}

extern "C" void kernel_launch(void* const* d_in, const int* in_sizes, int n_in,
                              void* d_out, int out_size, void* d_ws, size_t ws_size,
                              hipStream_t stream) {
  const float* F    = (const float*)d_in[0];   // [3136,512]
  const float* Wqkv = (const float*)d_in[1];   // [1536,512]
  const float* bqkv = (const float*)d_in[2];   // [1536]
  const float* Wo   = (const float*)d_in[3];   // [512,512]
  const float* bo   = (const float*)d_in[4];   // [512]
  const float* W1   = (const float*)d_in[5];   // [512,512]
  const float* b1   = (const float*)d_in[6];   // [512]
  const float* lng  = (const float*)d_in[7];   // [512]
  const float* lnb  = (const float*)d_in[8];   // [512]
  const float* W2   = (const float*)d_in[9];   // [20,512]
  const float* b2   = (const float*)d_in[10];  // [20]
  const float* Tm   = (const float*)d_in[11];  // [20,512]
  float* out = (float*)d_out;

  float* ws = (float*)d_ws;
  // Dedicated regions (R11/R14-proven layout):
  float* qkvw   = ws;                          // [3136,2048] = 6,422,528
  float* scores = ws + 6422528;                // 4,917,248
  float* Vt     = ws + 11339776;               // 128*64*224 = 1,835,008
  float* h1p    = ws + 13174784;               // 4 x 1,605,632 = 6,422,528
  float* Qp     = ws + 19597312;               //    62,720
  float* bcomb  = ws + 19660032;               //       512
  float* biasAll= ws + 19660544;               //     2,048
  unsigned long long* masks = (unsigned long long*)(ws + 19662592);  // 1,003,520 fl
  float* qifb   = ws + 20666112;               //    62,720
  unsigned short* Fs    = (unsigned short*)(ws + 20728832);  // 2,408,448 fl
  unsigned short* Walls = (unsigned short*)(ws + 23137280);  // 1,572,864 fl
  unsigned short* Wcs   = (unsigned short*)(ws + 24710144);  //   393,216 fl
  unsigned short* Omgs  = (unsigned short*)(ws + 25103360);  // 2,408,448 fl
  dim3 blk(256);

  // 1) prep: limb splits (F, Wqkv+W1 -> Walls), Wc = W1@Wo -> limbs,
  //    Vt pad zero, bcomb, biasAll
  prep_kernel<<<dim3(1474), blk, 0, stream>>>(
      F, Fs, Wqkv, W1, Walls, Wo, Wcs, Vt, bo, b1, bcomb, bqkv, biasAll);

  // 2) qkvw = F @ [Wqkv;W1]^T + biasAll      [3136,2048]  (pre-split MFMA)
  //    cols [0,1024): Q,K -> qkvw; [1024,1536): V -> Vt transposed;
  //    [1536,2048): F@W1^T -> qkvw (res for h1)
  gemm_ps3_kernel<<<dim3(25, 16, 1), blk, 0, stream>>>(
      Fs, Walls, qkvw, biasAll, nullptr,
      3136, 2048, 2048, 0, 1605632LL, 1048576LL, 512, 0LL, Vt);

  // 3) scores[b,h] = Q[b,h] @ K[b,h]^T       [196,196] x 128  (on-the-fly)
  gemm_bf16x3_kernel<<<dim3(2, 2, 128), blk, 0, stream>>>(
      qkvw, qkvw + 512, scores, nullptr, nullptr,
      196, 196, 64, 2048, 2048, 196,
      8, 196LL * 2048, 64, 196LL * 2048, 64, 8LL * 38416, 38416,
      nullptr, 0);

  // 4) softmax rows (scale 0.125 inside)
  softmax_kernel<<<dim3(6272), blk, 0, stream>>>(scores);

  // 5) O[b,h] = P[b,h] @ Vt[b,h]^T -> Omg LIMBS directly
  gemm_bf16x3_kernel<<<dim3(2, 1, 128), blk, 0, stream>>>(
      scores, Vt, nullptr, nullptr, nullptr,
      196, 64, 196, 196, 224, 512,
      8, 8LL * 38416, 38416, 8LL * 14336, 14336, 100352, 64,
      Omgs, 1605632LL);

  // 6) h1 = Omg @ Wc^T + FW1 + bcomb, split-K x4 -> 4 partials
  gemm_ps3_kernel<<<dim3(25, 4, 4), blk, 0, stream>>>(
      Omgs, Wcs, h1p, bcomb, qkvw + 1536,
      3136, 512, 512, 2048, 1605632LL, 262144LL, 128, 1605632LL, nullptr);

  // 7) fused LayerNorm + exact GELU + w2 -> Qp  (sums 4 partials)
  lnw2_kernel<<<dim3(3136), blk, 0, stream>>>(h1p, lng, lnb, W2, b2, Qp);

  // 8) selection: 2 tasks/wave, guarded quaternary search
  topk_select_kernel<<<dim3(7840), blk, 0, stream>>>(F, Tm, Qp, masks, qifb);

  // 9) streaming writeout of [B,N,D,M], 2 blocks per bn
  topk_write_kernel<<<dim3(6272), blk, 0, stream>>>(F, Tm, masks, qifb, out);
}